// Round 13
// baseline (40.138 us; speedup 1.0000x reference)
//
#include <hip/hip_runtime.h>
#include <math.h>

#define SEQ    8
#define DFF    32
#define VOCAB  256
#define BATCH  131072
#define CHUNKS 4          // chunks per wave; wave owns 32 contiguous rows

// Abramowitz-Stegun 7.1.26 erf (|err| <= 1.5e-7), exp2-based -> exact-GELU
__device__ __forceinline__ float gelu_f(float t) {
    float ax = fabsf(t);
    float k  = __builtin_amdgcn_rcpf(fmaf(0.3275911f, ax, 1.0f));
    float p  = fmaf(k, 1.061405429f, -1.453152027f);
    p = fmaf(k, p, 1.421413741f);
    p = fmaf(k, p, -0.284496736f);
    p = fmaf(k, p, 0.254829592f);
    p = p * k;
    float e  = __builtin_amdgcn_exp2f(-1.44269504f * ax * ax);
    float er = copysignf(fmaf(-p, e, 1.0f), t);     // erf(t)
    return 0.5f * t * (1.0f + er);
}

// Single-generation pipelined kernel: grid 1024 (4 blocks/CU, all resident).
// Each wave: 4 x {compute 8 elements (8 lanes each) -> issue 8 x 1 KiB stores}.
// Stores are non-blocking, so chunk c+1's compute overlaps chunk c's stores and
// waves desync -> store traffic is continuous instead of generation-bursty.
__global__ __launch_bounds__(256, 8) void seqtx_pipe(
    const int*   __restrict__ x,
    const float* __restrict__ Wqkv, const float* __restrict__ bqkv,
    const float* __restrict__ Wo,   const float* __restrict__ bo,
    const float* __restrict__ W1,   const float* __restrict__ b1,
    const float* __restrict__ W2,   const float* __restrict__ b2,
    const float* __restrict__ g1,   const float* __restrict__ be1,
    const float* __restrict__ g2,   const float* __restrict__ be2,
    const float* __restrict__ Wout, const float* __restrict__ bout,
    float* __restrict__ out)
{
    __shared__ float4 exch[256];                // per-8-lane-group kv slots

    const int tid   = threadIdx.x;
    const int lane  = tid & 63;
    const int wid   = tid >> 6;                 // wave in block
    const int sub   = tid & 7;                  // position within element
    const int g8    = (tid >> 3) & 7;
    const int gbase = tid & ~7;
    const int cg    = lane * 4;                 // vocab quad

    // ---- epilogue weights, chunk-invariant (folded LN2 + Wout) ----
    const float2* wvp = reinterpret_cast<const float2*>(Wout);
    float2 wv0 = wvp[cg + 0];
    float2 wv1 = wvp[cg + 1];
    float2 wv2 = wvp[cg + 2];
    float2 wv3 = wvp[cg + 3];
    float4 bv  = *reinterpret_cast<const float4*>(bout + cg);
    float gf0 = g2[2], gf1 = g2[3], bf0 = be2[2], bf1 = be2[3];
    float u0 = wv0.x * gf0 - wv0.y * gf1,  w0 = fmaf(wv0.x, bf0, fmaf(wv0.y, bf1, bv.x));
    float u1 = wv1.x * gf0 - wv1.y * gf1,  w1 = fmaf(wv1.x, bf0, fmaf(wv1.y, bf1, bv.y));
    float u2 = wv2.x * gf0 - wv2.y * gf1,  w2 = fmaf(wv2.x, bf0, fmaf(wv2.y, bf1, bv.z));
    float u3 = wv3.x * gf0 - wv3.y * gf1,  w3 = fmaf(wv3.x, bf0, fmaf(wv3.y, bf1, bv.w));

    int ebase = (blockIdx.x * 4 + wid) * 32;    // wave's first element (row)

    for (int c = 0; c < CHUNKS; ++c, ebase += 8) {
        // ---- load this chunk's tokens: 64 consecutive ints per wave ----
        float h0 = (float)x[ebase * SEQ + lane] * (1.0f / 255.0f);
        float h1 = (float)sub * (1.0f / 7.0f);
        float ndl;

        // ================= layer 0 (all positions) =================
        {
            const float* wq = Wqkv;
            const float* bq = bqkv;
            float q0 = fmaf(wq[0],  h0, fmaf(wq[1],  h1, bq[0]));
            float q1 = fmaf(wq[2],  h0, fmaf(wq[3],  h1, bq[1]));
            float k0 = fmaf(wq[4],  h0, fmaf(wq[5],  h1, bq[2]));
            float k1 = fmaf(wq[6],  h0, fmaf(wq[7],  h1, bq[3]));
            float v0 = fmaf(wq[8],  h0, fmaf(wq[9],  h1, bq[4]));
            float v1 = fmaf(wq[10], h0, fmaf(wq[11], h1, bq[5]));

            __builtin_amdgcn_wave_barrier();    // order vs prev chunk's reads
            exch[gbase | ((sub + g8) & 7)] = make_float4(k0, v0, k1, v1);
            __builtin_amdgcn_wave_barrier();    // order vs this chunk's reads

            float q0e = q0 * 1.44269504f;
            float q1e = q1 * 1.44269504f;
            float s0 = 0.0f, a0 = 0.0f, s1 = 0.0f, a1 = 0.0f;
            #pragma unroll
            for (int j = 0; j < SEQ; ++j) {
                float4 kv = exch[gbase | ((j + g8) & 7)];
                float e0 = __builtin_amdgcn_exp2f(q0e * kv.x);
                s0 += e0;  a0 = fmaf(e0, kv.y, a0);
                float e1 = __builtin_amdgcn_exp2f(q1e * kv.z);
                s1 += e1;  a1 = fmaf(e1, kv.w, a1);
            }
            float o0 = a0 * __builtin_amdgcn_rcpf(s0);
            float o1 = a1 * __builtin_amdgcn_rcpf(s1);

            float p0 = fmaf(Wo[0], o0, fmaf(Wo[1], o1, bo[0]));
            float p1 = fmaf(Wo[2], o0, fmaf(Wo[3], o1, bo[1]));
            float a = h0 + p0, cc = h1 + p1;
            float d = 0.5f * (a - cc);
            float nd = d * __builtin_amdgcn_rsqf(fmaf(d, d, 1e-5f));
            h0 = fmaf( nd, g1[0], be1[0]);
            h1 = fmaf(-nd, g1[1], be1[1]);

            // ---- FF direct: 32 GELU terms, thread-uniform weights (SGPR) ----
            float f0 = b2[0], f1 = b2[1];
            for (int j = 0; j < DFF; ++j) {
                float t = fmaf(W1[j * 2], h0, fmaf(W1[j * 2 + 1], h1, b1[j]));
                float g = gelu_f(t);
                f0 = fmaf(g, W2[j], f0);
                f1 = fmaf(g, W2[32 + j], f1);
            }

            a = h0 + f0;  cc = h1 + f1;
            d = 0.5f * (a - cc);
            float nd2 = d * __builtin_amdgcn_rsqf(fmaf(d, d, 1e-5f));
            h0 = fmaf( nd2, g2[0], be2[0]);
            h1 = fmaf(-nd2, g2[1], be2[1]);
        }

        // ================= layer 1 (only query position 7 consumed) =================
        {
            const float* wq = Wqkv + 12;
            const float* bq = bqkv + 6;
            float q0 = fmaf(wq[0],  h0, fmaf(wq[1],  h1, bq[0]));
            float q1 = fmaf(wq[2],  h0, fmaf(wq[3],  h1, bq[1]));
            float k0 = fmaf(wq[4],  h0, fmaf(wq[5],  h1, bq[2]));
            float k1 = fmaf(wq[6],  h0, fmaf(wq[7],  h1, bq[3]));
            float v0 = fmaf(wq[8],  h0, fmaf(wq[9],  h1, bq[4]));
            float v1 = fmaf(wq[10], h0, fmaf(wq[11], h1, bq[5]));

            float q0e = __shfl(q0, 7, SEQ) * 1.44269504f;
            float q1e = __shfl(q1, 7, SEQ) * 1.44269504f;
            float e0 = __builtin_amdgcn_exp2f(q0e * k0);
            float e1 = __builtin_amdgcn_exp2f(q1e * k1);
            float n0 = e0 * v0, n1 = e1 * v1;
            #pragma unroll
            for (int m = 1; m < SEQ; m <<= 1) {
                e0 += __shfl_xor(e0, m, SEQ);
                n0 += __shfl_xor(n0, m, SEQ);
                e1 += __shfl_xor(e1, m, SEQ);
                n1 += __shfl_xor(n1, m, SEQ);
            }
            float o0 = n0 * __builtin_amdgcn_rcpf(e0);   // uniform in 8-lane group
            float o1 = n1 * __builtin_amdgcn_rcpf(e1);

            float hp0 = __shfl(h0, 7, SEQ);
            float hp1 = __shfl(h1, 7, SEQ);
            float p0 = fmaf(Wo[4], o0, fmaf(Wo[5], o1, bo[2]));
            float p1 = fmaf(Wo[6], o0, fmaf(Wo[7], o1, bo[3]));
            float a = hp0 + p0, cc = hp1 + p1;
            float d = 0.5f * (a - cc);
            float nd = d * __builtin_amdgcn_rsqf(fmaf(d, d, 1e-5f));
            float hh0 = fmaf( nd, g1[2], be1[2]);        // uniform in group
            float hh1 = fmaf(-nd, g1[3], be1[3]);

            // ---- FF split across the 8-lane group: 4 GELU terms per lane ----
            float f0p = 0.0f, f1p = 0.0f;
            #pragma unroll
            for (int m = 0; m < 4; ++m) {
                int j = sub + m * 8;
                float t = fmaf(W1[64 + j * 2], hh0, fmaf(W1[64 + j * 2 + 1], hh1, b1[32 + j]));
                float g = gelu_f(t);
                f0p = fmaf(g, W2[64 + j], f0p);
                f1p = fmaf(g, W2[96 + j], f1p);
            }
            #pragma unroll
            for (int m = 1; m < SEQ; m <<= 1) {
                f0p += __shfl_xor(f0p, m, SEQ);
                f1p += __shfl_xor(f1p, m, SEQ);
            }
            float f0 = f0p + b2[2];
            float f1 = f1p + b2[3];

            a = hh0 + f0;  cc = hh1 + f1;
            d = 0.5f * (a - cc);
            ndl = d * __builtin_amdgcn_rsqf(fmaf(d, d, 1e-5f));  // uniform in group
        }

        // ---- stream this chunk's 8 rows (wave-contiguous 8 KiB) ----
        float* dst = out + (size_t)ebase * VOCAB + cg;
        #pragma unroll
        for (int e = 0; e < SEQ; ++e) {
            float ndv = __int_as_float(
                __builtin_amdgcn_readlane(__float_as_int(ndl), e * 8 + 7));
            float4 res;
            res.x = fmaf(ndv, u0, w0);
            res.y = fmaf(ndv, u1, w1);
            res.z = fmaf(ndv, u2, w2);
            res.w = fmaf(ndv, u3, w3);
            *reinterpret_cast<float4*>(dst) = res;
            dst += VOCAB;
        }
    }
}

extern "C" void kernel_launch(void* const* d_in, const int* in_sizes, int n_in,
                              void* d_out, int out_size, void* d_ws, size_t ws_size,
                              hipStream_t stream) {
    const int*   x    = (const int*)  d_in[0];
    const float* Wqkv = (const float*)d_in[1];
    const float* bqkv = (const float*)d_in[2];
    const float* Wo   = (const float*)d_in[3];
    const float* bo   = (const float*)d_in[4];
    const float* W1   = (const float*)d_in[5];
    const float* b1   = (const float*)d_in[6];
    const float* W2   = (const float*)d_in[7];
    const float* b2   = (const float*)d_in[8];
    const float* g1   = (const float*)d_in[9];
    const float* be1  = (const float*)d_in[10];
    const float* g2   = (const float*)d_in[11];
    const float* be2  = (const float*)d_in[12];
    const float* Wout = (const float*)d_in[13];
    const float* bout = (const float*)d_in[14];
    float* out = (float*)d_out;

    // 1024 blocks = 4/CU, single resident generation; each wave owns 32 rows
    seqtx_pipe<<<BATCH / (32 * CHUNKS), 256, 0, stream>>>(
        x, Wqkv, bqkv, Wo, bo, W1, b1, W2, b2, g1, be1, g2, be2, Wout, bout, out);
}

// Round 14
// 32.888 us; speedup vs baseline: 1.2204x; 1.2204x over previous
//
#include <hip/hip_runtime.h>
#include <math.h>

#define SEQ   8
#define DFF   32
#define NL    2
#define VOCAB 256
#define BATCH 131072
#define TBL_N 256    // intervals/layer; 2*256 float4 = 8 KiB LDS

// Parallel table builder: one 32-lane half-wave per entry; lane j computes the
// j-th GELU term at both interval endpoints, butterfly-reduce, lane 0 writes.
__global__ __launch_bounds__(256) void build_tables_par(
    const float* __restrict__ W1, const float* __restrict__ b1,
    const float* __restrict__ W2, const float* __restrict__ b2,
    const float* __restrict__ g1, const float* __restrict__ be1,
    float4* __restrict__ T4)
{
    int gt    = blockIdx.x * 256 + threadIdx.x;
    int entry = gt >> 5;
    int j     = gt & 31;
    if (entry >= NL * TBL_N) return;
    int l = entry >> 8;
    int i = entry & (TBL_N - 1);

    float nd0 = -1.0f + (float)i * (2.0f / TBL_N);
    float nd1 = nd0 + (2.0f / TBL_N);

    float ga = g1[l*2+0], gb = g1[l*2+1], ba = be1[l*2+0], bb = be1[l*2+1];
    float w1a = W1[l*64 + j*2], w1b = W1[l*64 + j*2 + 1], b1j = b1[l*32 + j];
    float w2a = W2[l*64 + j],   w2b = W2[l*64 + 32 + j];

    float h0 = fmaf( nd0, ga, ba), h1 = fmaf(-nd0, gb, bb);
    float t  = fmaf(w1a, h0, fmaf(w1b, h1, b1j));
    float g  = 0.5f * t * (1.0f + erff(t * 0.70710678118654752f));
    float f00 = g * w2a, f10 = g * w2b;
    h0 = fmaf( nd1, ga, ba); h1 = fmaf(-nd1, gb, bb);
    t  = fmaf(w1a, h0, fmaf(w1b, h1, b1j));
    g  = 0.5f * t * (1.0f + erff(t * 0.70710678118654752f));
    float f01 = g * w2a, f11 = g * w2b;

    #pragma unroll
    for (int m = 1; m < 32; m <<= 1) {
        f00 += __shfl_xor(f00, m, 32);
        f10 += __shfl_xor(f10, m, 32);
        f01 += __shfl_xor(f01, m, 32);
        f11 += __shfl_xor(f11, m, 32);
    }
    if (j == 0) {
        T4[entry] = make_float4(f00 + b2[l*2+0], f10 + b2[l*2+1],
                                f01 + b2[l*2+0], f11 + b2[l*2+1]);
    }
}

// Grid 2048 = exactly 8 blocks/CU: ONE residency generation (no convoy).
// Each wave owns 16 contiguous rows, processed as 2 chunks of 8:
// {compute 8 elements -> issue 8 x 1 KiB stores} x2; chunk-1 compute overlaps
// chunk-0's in-flight stores. Both token loads issued before any compute.
__global__ __launch_bounds__(256, 8) void seqtx_main(
    const int*   __restrict__ x,
    const float* __restrict__ Wqkv, const float* __restrict__ bqkv,
    const float* __restrict__ Wo,   const float* __restrict__ bo,
    const float* __restrict__ g1,   const float* __restrict__ be1,
    const float* __restrict__ g2,   const float* __restrict__ be2,
    const float* __restrict__ Wout, const float* __restrict__ bout,
    const float4* __restrict__ T4,
    float* __restrict__ out)
{
    __shared__ float4 tbl[NL * TBL_N];          // 8 KiB
    __shared__ float4 exch[256];                // 4 KiB

    const int tid    = threadIdx.x;
    const int sub    = tid & 7;
    const int lane   = tid & 63;
    const int wid    = tid >> 6;
    const int g8     = (tid >> 3) & 7;
    const int gbase  = tid & ~7;
    const int cg     = lane * 4;
    const int waveid = blockIdx.x * 4 + wid;
    const int rb0    = waveid * 16;             // wave's first row

    // stage table: 512 float4 entries, 2 coalesced 16B loads/thread
    tbl[tid]       = T4[tid];
    tbl[tid + 256] = T4[tid + 256];

    // both chunks' tokens issued up front
    float xt0 = (float)x[rb0 * SEQ + lane];
    float xt1 = (float)x[(rb0 + 8) * SEQ + lane];

    // epilogue weights (chunk-invariant, folded LN2+Wout)
    const float2* wvp = reinterpret_cast<const float2*>(Wout);
    float2 wv0 = wvp[cg + 0];
    float2 wv1 = wvp[cg + 1];
    float2 wv2 = wvp[cg + 2];
    float2 wv3 = wvp[cg + 3];
    float4 bv  = *reinterpret_cast<const float4*>(bout + cg);
    float gf0 = g2[2], gf1 = g2[3], bf0 = be2[2], bf1 = be2[3];
    float u0 = wv0.x * gf0 - wv0.y * gf1,  w0 = fmaf(wv0.x, bf0, fmaf(wv0.y, bf1, bv.x));
    float u1 = wv1.x * gf0 - wv1.y * gf1,  w1 = fmaf(wv1.x, bf0, fmaf(wv1.y, bf1, bv.y));
    float u2 = wv2.x * gf0 - wv2.y * gf1,  w2 = fmaf(wv2.x, bf0, fmaf(wv2.y, bf1, bv.z));
    float u3 = wv3.x * gf0 - wv3.y * gf1,  w3 = fmaf(wv3.x, bf0, fmaf(wv3.y, bf1, bv.w));

    __syncthreads();                            // table visible

    #pragma unroll
    for (int c = 0; c < 2; ++c) {
        float h0 = (c ? xt1 : xt0) * (1.0f / 255.0f);
        float h1 = (float)sub * (1.0f / 7.0f);
        float ndl;

        // ================= layer 0 (all positions) =================
        {
            const float* wq = Wqkv;
            const float* bq = bqkv;
            float q0 = fmaf(wq[0],  h0, fmaf(wq[1],  h1, bq[0]));
            float q1 = fmaf(wq[2],  h0, fmaf(wq[3],  h1, bq[1]));
            float k0 = fmaf(wq[4],  h0, fmaf(wq[5],  h1, bq[2]));
            float k1 = fmaf(wq[6],  h0, fmaf(wq[7],  h1, bq[3]));
            float v0 = fmaf(wq[8],  h0, fmaf(wq[9],  h1, bq[4]));
            float v1 = fmaf(wq[10], h0, fmaf(wq[11], h1, bq[5]));

            __builtin_amdgcn_wave_barrier();    // order vs prev chunk's exch reads
            exch[gbase | ((sub + g8) & 7)] = make_float4(k0, v0, k1, v1);
            __builtin_amdgcn_wave_barrier();    // order vs this chunk's reads

            float q0e = q0 * 1.44269504f;
            float q1e = q1 * 1.44269504f;
            float s0 = 0.0f, a0 = 0.0f, s1 = 0.0f, a1 = 0.0f;
            #pragma unroll
            for (int j = 0; j < SEQ; ++j) {
                float4 kv = exch[gbase | ((j + g8) & 7)];
                float e0 = __builtin_amdgcn_exp2f(q0e * kv.x);
                s0 += e0;  a0 = fmaf(e0, kv.y, a0);
                float e1 = __builtin_amdgcn_exp2f(q1e * kv.z);
                s1 += e1;  a1 = fmaf(e1, kv.w, a1);
            }
            float o0 = a0 * __builtin_amdgcn_rcpf(s0);
            float o1 = a1 * __builtin_amdgcn_rcpf(s1);

            float p0 = fmaf(Wo[0], o0, fmaf(Wo[1], o1, bo[0]));
            float p1 = fmaf(Wo[2], o0, fmaf(Wo[3], o1, bo[1]));
            float a = h0 + p0, cc = h1 + p1;
            float d = 0.5f * (a - cc);
            float nd = d * __builtin_amdgcn_rsqf(fmaf(d, d, 1e-5f));
            h0 = fmaf( nd, g1[0], be1[0]);
            h1 = fmaf(-nd, g1[1], be1[1]);

            float tf = fmaf(nd, (float)(TBL_N / 2), (float)(TBL_N / 2));
            int   i  = (int)tf;
            i = (i < 0) ? 0 : ((i > TBL_N - 1) ? TBL_N - 1 : i);
            float fr = tf - (float)i;
            float4 e4 = tbl[i];
            float f0 = fmaf(fr, e4.z - e4.x, e4.x);
            float f1 = fmaf(fr, e4.w - e4.y, e4.y);

            a = h0 + f0;  cc = h1 + f1;
            d = 0.5f * (a - cc);
            float nd2 = d * __builtin_amdgcn_rsqf(fmaf(d, d, 1e-5f));
            h0 = fmaf( nd2, g2[0], be2[0]);
            h1 = fmaf(-nd2, g2[1], be2[1]);
        }

        // ================= layer 1 (only query position 7 consumed) =================
        {
            const float* wq = Wqkv + 12;
            const float* bq = bqkv + 6;
            float q0 = fmaf(wq[0],  h0, fmaf(wq[1],  h1, bq[0]));
            float q1 = fmaf(wq[2],  h0, fmaf(wq[3],  h1, bq[1]));
            float k0 = fmaf(wq[4],  h0, fmaf(wq[5],  h1, bq[2]));
            float k1 = fmaf(wq[6],  h0, fmaf(wq[7],  h1, bq[3]));
            float v0 = fmaf(wq[8],  h0, fmaf(wq[9],  h1, bq[4]));
            float v1 = fmaf(wq[10], h0, fmaf(wq[11], h1, bq[5]));

            float q0e = __shfl(q0, 7, SEQ) * 1.44269504f;
            float q1e = __shfl(q1, 7, SEQ) * 1.44269504f;
            float e0 = __builtin_amdgcn_exp2f(q0e * k0);
            float e1 = __builtin_amdgcn_exp2f(q1e * k1);
            float n0 = e0 * v0, n1 = e1 * v1;
            #pragma unroll
            for (int m = 1; m < SEQ; m <<= 1) {
                e0 += __shfl_xor(e0, m, SEQ);
                n0 += __shfl_xor(n0, m, SEQ);
                e1 += __shfl_xor(e1, m, SEQ);
                n1 += __shfl_xor(n1, m, SEQ);
            }
            float o0 = n0 * __builtin_amdgcn_rcpf(e0);   // uniform in 8-lane group
            float o1 = n1 * __builtin_amdgcn_rcpf(e1);

            float p0 = fmaf(Wo[4], o0, fmaf(Wo[5], o1, bo[2]));
            float p1 = fmaf(Wo[6], o0, fmaf(Wo[7], o1, bo[3]));
            float a = h0 + p0, cc = h1 + p1;             // only sub==7 meaningful
            float d = 0.5f * (a - cc);
            float nd = d * __builtin_amdgcn_rsqf(fmaf(d, d, 1e-5f));
            float hh0 = fmaf( nd, g1[2], be1[2]);
            float hh1 = fmaf(-nd, g1[3], be1[3]);

            float tf = fmaf(nd, (float)(TBL_N / 2), (float)(TBL_N / 2));
            int   i  = (int)tf;
            i = (i < 0) ? 0 : ((i > TBL_N - 1) ? TBL_N - 1 : i);
            float fr = tf - (float)i;
            float4 e4 = tbl[TBL_N + i];
            float f0 = fmaf(fr, e4.z - e4.x, e4.x);
            float f1 = fmaf(fr, e4.w - e4.y, e4.y);

            a = hh0 + f0;  cc = hh1 + f1;
            d = 0.5f * (a - cc);
            ndl = d * __builtin_amdgcn_rsqf(fmaf(d, d, 1e-5f));
        }

        // ---- stream this chunk's 8 rows (wave-contiguous 8 KiB), fire & forget ----
        float* dst = out + (size_t)(rb0 + c * 8) * VOCAB + cg;
        #pragma unroll
        for (int e = 0; e < SEQ; ++e) {
            float ndv = __int_as_float(
                __builtin_amdgcn_readlane(__float_as_int(ndl), e * 8 + 7));
            float4 res;
            res.x = fmaf(ndv, u0, w0);
            res.y = fmaf(ndv, u1, w1);
            res.z = fmaf(ndv, u2, w2);
            res.w = fmaf(ndv, u3, w3);
            *reinterpret_cast<float4*>(dst) = res;
            dst += VOCAB;
        }
    }
}

extern "C" void kernel_launch(void* const* d_in, const int* in_sizes, int n_in,
                              void* d_out, int out_size, void* d_ws, size_t ws_size,
                              hipStream_t stream) {
    const int*   x    = (const int*)  d_in[0];
    const float* Wqkv = (const float*)d_in[1];
    const float* bqkv = (const float*)d_in[2];
    const float* Wo   = (const float*)d_in[3];
    const float* bo   = (const float*)d_in[4];
    const float* W1   = (const float*)d_in[5];
    const float* b1   = (const float*)d_in[6];
    const float* W2   = (const float*)d_in[7];
    const float* b2   = (const float*)d_in[8];
    const float* g1   = (const float*)d_in[9];
    const float* be1  = (const float*)d_in[10];
    const float* g2   = (const float*)d_in[11];
    const float* be2  = (const float*)d_in[12];
    const float* Wout = (const float*)d_in[13];
    const float* bout = (const float*)d_in[14];
    float* out = (float*)d_out;

    float4* T4 = (float4*)d_ws;   // NL*TBL_N*16B = 8 KiB

    build_tables_par<<<(NL * TBL_N * 32) / 256, 256, 0, stream>>>(
        W1, b1, W2, b2, g1, be1, T4);

    // 2048 blocks = 8/CU exactly: one residency generation; wave owns 16 rows
    seqtx_main<<<BATCH / 64, 256, 0, stream>>>(
        x, Wqkv, bqkv, Wo, bo, g1, be1, g2, be2, Wout, bout, T4, out);
}